// Round 2
// baseline (27.367 us; speedup 1.0000x reference)
//
#include <hip/hip_runtime.h>

// DocumentBertScoringLoss: loss = MSE + MR + SIM over B=8192 fp32 vectors.
// MR term simplifies to mean over all (m,n) of max(0, 0.1 - |p_m - p_n|)
// (verified round 1, absmax 0.0). Single fused kernel: pairwise partials +
// linear partials, last block (ticket) combines deterministically.

#define B_N 8192
#define THREADS 256
#define M_PER_THREAD 2
#define MB (THREADS * M_PER_THREAD)   // 512 m-rows per block
#define NXB (B_N / MB)                // 16 m-chunks
#define CHUNK 256                     // n's staged in LDS per block
#define NYB (B_N / CHUNK)             // 32 n-chunks
#define NBLOCKS (NXB * NYB)           // 512 blocks = 2/CU = 8 waves/CU

__device__ __forceinline__ float block_reduce_sum(float v, float* sbuf) {
    #pragma unroll
    for (int off = 32; off > 0; off >>= 1)
        v += __shfl_down(v, off, 64);
    const int lane = threadIdx.x & 63;
    const int wave = threadIdx.x >> 6;
    if (lane == 0) sbuf[wave] = v;
    __syncthreads();
    if (threadIdx.x == 0) {
        float s = 0.f;
        #pragma unroll
        for (int w = 0; w < THREADS / 64; ++w) s += sbuf[w];
        sbuf[0] = s;
    }
    __syncthreads();
    const float r = sbuf[0];
    __syncthreads();   // sbuf reusable by caller afterwards
    return r;
}

__global__ void __launch_bounds__(THREADS)
fused_loss_kernel(const float* __restrict__ p, const float* __restrict__ g,
                  float* __restrict__ pairPartial,   // [NBLOCKS]
                  float* __restrict__ linPartial,    // [NXB*4]
                  unsigned int* __restrict__ counter,
                  float* __restrict__ out) {
    __shared__ float s_n[CHUNK];
    __shared__ float sbuf[THREADS / 64];
    __shared__ int s_last;

    const int tid = threadIdx.x;
    const int bx = blockIdx.x, by = blockIdx.y;
    const int m0 = bx * MB + tid;          // coalesced
    const int m1 = m0 + THREADS;

    s_n[tid] = p[by * CHUNK + tid];
    const float pm0 = p[m0];
    const float pm1 = p[m1];
    __syncthreads();

    // 8 independent accumulators: short dep chains, ds_read_b128 LDS reads.
    float a00 = 0.f, a01 = 0.f, a02 = 0.f, a03 = 0.f;
    float a10 = 0.f, a11 = 0.f, a12 = 0.f, a13 = 0.f;
    const float4* s4 = (const float4*)s_n;
    #pragma unroll 4
    for (int j = 0; j < CHUNK / 4; ++j) {
        const float4 v = s4[j];            // uniform addr -> broadcast, no conflicts
        a00 += fmaxf(0.f, 0.1f - fabsf(pm0 - v.x));
        a01 += fmaxf(0.f, 0.1f - fabsf(pm0 - v.y));
        a02 += fmaxf(0.f, 0.1f - fabsf(pm0 - v.z));
        a03 += fmaxf(0.f, 0.1f - fabsf(pm0 - v.w));
        a10 += fmaxf(0.f, 0.1f - fabsf(pm1 - v.x));
        a11 += fmaxf(0.f, 0.1f - fabsf(pm1 - v.y));
        a12 += fmaxf(0.f, 0.1f - fabsf(pm1 - v.z));
        a13 += fmaxf(0.f, 0.1f - fabsf(pm1 - v.w));
    }
    const float acc = ((a00 + a01) + (a02 + a03)) + ((a10 + a11) + (a12 + a13));
    const float s = block_reduce_sum(acc, sbuf);
    if (tid == 0) pairPartial[by * NXB + bx] = s;

    if (by == 0) {                          // block-uniform branch
        const float gv0 = g[m0], gv1 = g[m1];
        const float d0 = pm0 - gv0, d1 = pm1 - gv1;
        float sq  = d0 * d0 + d1 * d1;
        float dot = pm0 * gv0 + pm1 * gv1;
        float npp = pm0 * pm0 + pm1 * pm1;
        float ngg = gv0 * gv0 + gv1 * gv1;
        sq  = block_reduce_sum(sq, sbuf);
        dot = block_reduce_sum(dot, sbuf);
        npp = block_reduce_sum(npp, sbuf);
        ngg = block_reduce_sum(ngg, sbuf);
        if (tid == 0) {
            linPartial[bx * 4 + 0] = sq;
            linPartial[bx * 4 + 1] = dot;
            linPartial[bx * 4 + 2] = npp;
            linPartial[bx * 4 + 3] = ngg;
        }
    }

    // Ticket: last finished block combines all partials (fixed order -> deterministic).
    if (tid == 0) {
        __threadfence();                    // device-scope release of partial stores
        const unsigned int t = atomicAdd(counter, 1u);
        s_last = (t == NBLOCKS - 1);
    }
    __syncthreads();
    if (!s_last) return;

    float mr = 0.f;
    for (int i = tid; i < NBLOCKS; i += THREADS)
        mr += __hip_atomic_load(&pairPartial[i], __ATOMIC_RELAXED,
                                __HIP_MEMORY_SCOPE_AGENT);
    mr = block_reduce_sum(mr, sbuf);

    float lv[4];
    #pragma unroll
    for (int k = 0; k < 4; ++k) {
        float v = 0.f;
        if (tid < NXB)
            v = __hip_atomic_load(&linPartial[tid * 4 + k], __ATOMIC_RELAXED,
                                  __HIP_MEMORY_SCOPE_AGENT);
        lv[k] = block_reduce_sum(v, sbuf);
    }

    if (tid == 0) {
        const float mse = lv[0] / (float)B_N;
        const float mrm = mr / ((float)B_N * (float)B_N);
        const float denom = fmaxf(sqrtf(lv[2]) * sqrtf(lv[3]), 1e-8f);
        const float sim = 1.f - lv[1] / denom;
        out[0] = mse + mrm + sim;           // alpha = beta = gamma = 1
    }
}

extern "C" void kernel_launch(void* const* d_in, const int* in_sizes, int n_in,
                              void* d_out, int out_size, void* d_ws, size_t ws_size,
                              hipStream_t stream) {
    const float* p = (const float*)d_in[0];
    const float* g = (const float*)d_in[1];
    float* pairPartial = (float*)d_ws;                            // 512 floats
    float* linPartial  = (float*)d_ws + NBLOCKS;                  // 64 floats
    unsigned int* counter = (unsigned int*)((char*)d_ws + 4096);  // 4 bytes

    // ws is poisoned once (0xAA) and never re-poisoned between replays:
    // reset the ticket counter every call (graph-capturable memset node).
    hipMemsetAsync(counter, 0, sizeof(unsigned int), stream);

    dim3 grid(NXB, NYB);
    fused_loss_kernel<<<grid, THREADS, 0, stream>>>(
        p, g, pairPartial, linPartial, counter, (float*)d_out);
}